// Round 1
// baseline (3584.293 us; speedup 1.0000x reference)
//
#include <hip/hip_runtime.h>

#define NN 100000
#define IN_CH 128
#define HID 32
#define OUT_CH 64
#define N_LAYERS 16
#define NB1 1280            // grid-stride blocks for k_agg
#define EPS_MSG 1e-7f
#define EPS_SM 1e-16f
#define EPS_BN 1e-5f

// ---------------- CSR build ----------------

__global__ void k_hist(const int* __restrict__ dst, int* __restrict__ counts, int E) {
    int i = blockIdx.x * 256 + threadIdx.x;
    if (i < E) atomicAdd(&counts[dst[i]], 1);
}

__global__ void k_scan1(const int* __restrict__ counts, int* __restrict__ rowptr,
                        int* __restrict__ bsum, int n) {
    __shared__ int sh[1024];
    int t = threadIdx.x;
    int i = blockIdx.x * 1024 + t;
    int v = (i < n) ? counts[i] : 0;
    sh[t] = v;
    __syncthreads();
    for (int off = 1; off < 1024; off <<= 1) {
        int tmp = (t >= off) ? sh[t - off] : 0;
        __syncthreads();
        sh[t] += tmp;
        __syncthreads();
    }
    if (i < n) rowptr[i] = sh[t] - v;   // exclusive within chunk
    if (t == 1023) bsum[blockIdx.x] = sh[1023];
}

__global__ void k_scan2(int* __restrict__ bsum, int nb) {
    if (threadIdx.x == 0 && blockIdx.x == 0) {
        int acc = 0;
        for (int b = 0; b < nb; b++) { int v = bsum[b]; bsum[b] = acc; acc += v; }
    }
}

__global__ void k_scan3(int* __restrict__ rowptr, int* __restrict__ cursor,
                        const int* __restrict__ bsum, int n, int E) {
    int i = blockIdx.x * 256 + threadIdx.x;
    if (i < n) {
        int r = rowptr[i] + bsum[i >> 10];
        rowptr[i] = r;
        cursor[i] = r;
    }
    if (i == 0) rowptr[n] = E;
}

__global__ void k_scatter(const int* __restrict__ src, const int* __restrict__ dst,
                          int* __restrict__ cursor, int* __restrict__ col, int E) {
    int i = blockIdx.x * 256 + threadIdx.x;
    if (i < E) {
        int d = dst[i];
        int p = atomicAdd(&cursor[d], 1);
        col[p] = src[i];
    }
}

// ---------------- input projection: h0 = x @ w0 + b0 ----------------

__global__ __launch_bounds__(256) void k0(const float* __restrict__ x,
                                          const float* __restrict__ w0,
                                          const float* __restrict__ b0,
                                          float* __restrict__ h) {
    __shared__ float ws[IN_CH * HID];   // 16 KB
    __shared__ float xs[8][IN_CH];      // 4 KB
    int tid = threadIdx.x, c = tid & 31, g = tid >> 5;
    for (int k = tid; k < IN_CH * HID; k += 256) ws[k] = w0[k];
    int d = blockIdx.x * 8 + g;
    float4 xv = ((const float4*)(x + (size_t)d * IN_CH))[c];
    ((float4*)xs[g])[c] = xv;
    __syncthreads();
    float acc = b0[c];
#pragma unroll 16
    for (int k = 0; k < IN_CH; k++) acc += xs[g][k] * ws[k * HID + c];
    h[(size_t)d * HID + c] = acc;
}

// ---------------- per-layer: softmax-agg + residual + lin1 + BN partial sums ----------------

__global__ __launch_bounds__(256) void k_agg(const float* __restrict__ h,
                                             const int* __restrict__ rowptr,
                                             const int* __restrict__ col,
                                             const float* __restrict__ w1,
                                             const float* __restrict__ b1,
                                             float* __restrict__ z,
                                             float* __restrict__ partials,
                                             int layer) {
    __shared__ float w1s[HID * 64];   // 8 KB
    __shared__ float b1s[64];
    __shared__ float outs[8][HID];
    __shared__ float red[256];
    int tid = threadIdx.x, c = tid & 31, g = tid >> 5;
    for (int k = tid; k < HID * 64; k += 256) w1s[k] = w1[layer * (HID * 64) + k];
    if (tid < 64) b1s[tid] = b1[layer * 64 + tid];
    float s0 = 0.f, s1 = 0.f, q0 = 0.f, q1 = 0.f;
    __syncthreads();

    for (int d0 = blockIdx.x * 8; d0 < NN; d0 += NB1 * 8) {
        int d = d0 + g;
        float out = 0.f;
        if (d < NN) {
            int r0 = rowptr[d], r1 = rowptr[d + 1];
            float den = 0.f, num = 0.f;
            for (int e = r0; e < r1; e++) {
                int s = col[e];
                float v = fmaxf(h[(size_t)s * HID + c], 0.f) + EPS_MSG;
                float ev = __expf(v);     // bounded: no max-subtraction needed
                den += ev;
                num += ev * v;
            }
            out = num / (den + EPS_SM) + h[(size_t)d * HID + c];
        }
        outs[g][c] = out;
        __syncthreads();
        if (d < NN) {
            float z0 = b1s[c], z1 = b1s[c + 32];
#pragma unroll
            for (int k = 0; k < HID; k++) {
                float o = outs[g][k];
                z0 += o * w1s[k * 64 + c];
                z1 += o * w1s[k * 64 + c + 32];
            }
            z[(size_t)d * 64 + c] = z0;
            z[(size_t)d * 64 + 32 + c] = z1;
            s0 += z0; s1 += z1; q0 += z0 * z0; q1 += z1 * z1;
        }
        __syncthreads();
    }

    // block-level reduce of BN partial sums (channels 0..63: sum, then sumsq)
    int b = blockIdx.x;
    red[tid] = s0; __syncthreads();
    if (tid < 32) { float a = 0; for (int g2 = 0; g2 < 8; g2++) a += red[g2 * 32 + tid]; partials[b * 128 + tid] = a; }
    __syncthreads();
    red[tid] = s1; __syncthreads();
    if (tid < 32) { float a = 0; for (int g2 = 0; g2 < 8; g2++) a += red[g2 * 32 + tid]; partials[b * 128 + 32 + tid] = a; }
    __syncthreads();
    red[tid] = q0; __syncthreads();
    if (tid < 32) { float a = 0; for (int g2 = 0; g2 < 8; g2++) a += red[g2 * 32 + tid]; partials[b * 128 + 64 + tid] = a; }
    __syncthreads();
    red[tid] = q1; __syncthreads();
    if (tid < 32) { float a = 0; for (int g2 = 0; g2 < 8; g2++) a += red[g2 * 32 + tid]; partials[b * 128 + 96 + tid] = a; }
}

// ---------------- BN finalize: mean/var -> scale/shift ----------------

__global__ __launch_bounds__(1024) void k_bnfin(const float* __restrict__ partials,
                                                const float* __restrict__ gamma,
                                                const float* __restrict__ beta,
                                                float* __restrict__ bnsc,
                                                float* __restrict__ bnsh,
                                                int layer) {
    __shared__ double sS[1024];
    __shared__ double sQ[1024];
    int tid = threadIdx.x, j = tid & 63, sl = tid >> 6;
    double S = 0.0, Q = 0.0;
    for (int b = sl; b < NB1; b += 16) {
        S += (double)partials[b * 128 + j];
        Q += (double)partials[b * 128 + 64 + j];
    }
    sS[tid] = S; sQ[tid] = Q;
    __syncthreads();
    if (sl == 0) {
        for (int s2 = 1; s2 < 16; s2++) { S += sS[s2 * 64 + j]; Q += sQ[s2 * 64 + j]; }
        double mean = S / (double)NN;
        double var = Q / (double)NN - mean * mean;
        float sc = gamma[layer * 64 + j] * rsqrtf((float)var + EPS_BN);
        float sh = beta[layer * 64 + j] - (float)mean * sc;
        bnsc[j] = sc;
        bnsh[j] = sh;
    }
}

// ---------------- BN apply + relu + lin2 + relu ----------------

__global__ __launch_bounds__(256) void k_bn2(const float* __restrict__ z,
                                             const float* __restrict__ bnsc,
                                             const float* __restrict__ bnsh,
                                             const float* __restrict__ w2,
                                             const float* __restrict__ b2,
                                             float* __restrict__ hout,
                                             int layer) {
    __shared__ float w2s[64 * HID];   // 8 KB
    __shared__ float zs[8][64];
    __shared__ float scs[64], shs[64];
    int tid = threadIdx.x, c = tid & 31, g = tid >> 5;
    for (int k = tid; k < 64 * HID; k += 256) w2s[k] = w2[layer * (64 * HID) + k];
    if (tid < 64) { scs[tid] = bnsc[tid]; shs[tid] = bnsh[tid]; }
    __syncthreads();
    int d = blockIdx.x * 8 + g;
    float z0 = z[(size_t)d * 64 + c] * scs[c] + shs[c];
    float z1 = z[(size_t)d * 64 + 32 + c] * scs[c + 32] + shs[c + 32];
    zs[g][c] = fmaxf(z0, 0.f);
    zs[g][c + 32] = fmaxf(z1, 0.f);
    __syncthreads();
    float acc = b2[layer * HID + c];
#pragma unroll
    for (int k = 0; k < 64; k++) acc += zs[g][k] * w2s[k * HID + c];
    hout[(size_t)d * HID + c] = fmaxf(acc, 0.f);
}

// ---------------- output projection: out = h @ w16 + b16 ----------------

__global__ __launch_bounds__(256) void k_final(const float* __restrict__ h,
                                               const float* __restrict__ w16,
                                               const float* __restrict__ b16,
                                               float* __restrict__ out) {
    __shared__ float ws[HID * OUT_CH];   // 8 KB
    __shared__ float hs[8][HID];
    int tid = threadIdx.x, c = tid & 31, g = tid >> 5;
    for (int k = tid; k < HID * OUT_CH; k += 256) ws[k] = w16[k];
    int d = blockIdx.x * 8 + g;
    hs[g][c] = h[(size_t)d * HID + c];
    __syncthreads();
    float o0 = b16[c], o1 = b16[c + 32];
#pragma unroll
    for (int k = 0; k < HID; k++) {
        float hv = hs[g][k];
        o0 += hv * ws[k * OUT_CH + c];
        o1 += hv * ws[k * OUT_CH + c + 32];
    }
    out[(size_t)d * OUT_CH + c] = o0;
    out[(size_t)d * OUT_CH + 32 + c] = o1;
}

// ---------------- host ----------------

extern "C" void kernel_launch(void* const* d_in, const int* in_sizes, int n_in,
                              void* d_out, int out_size, void* d_ws, size_t ws_size,
                              hipStream_t stream) {
    const float* x      = (const float*)d_in[0];
    const int*   ei     = (const int*)d_in[1];
    const float* w0     = (const float*)d_in[2];
    const float* b0     = (const float*)d_in[3];
    const float* lin1_w = (const float*)d_in[4];
    const float* lin1_b = (const float*)d_in[5];
    const float* gamma  = (const float*)d_in[6];
    const float* beta   = (const float*)d_in[7];
    const float* lin2_w = (const float*)d_in[8];
    const float* lin2_b = (const float*)d_in[9];
    const float* w16    = (const float*)d_in[10];
    const float* b16    = (const float*)d_in[11];
    float* out = (float*)d_out;

    const int E = in_sizes[1] / 2;
    const int* src = ei;
    const int* dst = ei + E;

    // workspace carve-up (all 256B-aligned)
    char* p = (char*)d_ws;
    auto alloc = [&](size_t bytes) {
        char* q = p;
        p += (bytes + 255) & ~(size_t)255;
        return q;
    };
    float* hA       = (float*)alloc((size_t)NN * HID * 4);
    float* hB       = (float*)alloc((size_t)NN * HID * 4);
    float* z        = (float*)alloc((size_t)NN * 64 * 4);
    int*   rowptr   = (int*)alloc((size_t)(NN + 1) * 4);
    int*   cursor   = (int*)alloc((size_t)NN * 4);
    int*   counts   = (int*)alloc((size_t)NN * 4);
    int*   col      = (int*)alloc((size_t)E * 4);
    int*   bsum     = (int*)alloc(1024 * 4);
    float* partials = (float*)alloc((size_t)NB1 * 128 * 4);
    float* bnsc     = (float*)alloc(64 * 4);
    float* bnsh     = (float*)alloc(64 * 4);
    (void)ws_size; (void)n_in; (void)out_size;

    // --- CSR build (once per call; reused by all 16 layers) ---
    hipMemsetAsync(counts, 0, (size_t)NN * 4, stream);
    int egrid = (E + 255) / 256;
    k_hist<<<egrid, 256, 0, stream>>>(dst, counts, E);
    int b1g = (NN + 1023) / 1024;
    k_scan1<<<b1g, 1024, 0, stream>>>(counts, rowptr, bsum, NN);
    k_scan2<<<1, 1, 0, stream>>>(bsum, b1g);
    k_scan3<<<(NN + 255) / 256, 256, 0, stream>>>(rowptr, cursor, bsum, NN, E);
    k_scatter<<<egrid, 256, 0, stream>>>(src, dst, cursor, col, E);

    // --- input projection ---
    k0<<<NN / 8, 256, 0, stream>>>(x, w0, b0, hA);

    // --- 16 layers ---
    float* hin = hA;
    float* hout = hB;
    for (int i = 0; i < N_LAYERS; i++) {
        k_agg<<<NB1, 256, 0, stream>>>(hin, rowptr, col, lin1_w, lin1_b, z, partials, i);
        k_bnfin<<<1, 1024, 0, stream>>>(partials, gamma, beta, bnsc, bnsh, i);
        k_bn2<<<NN / 8, 256, 0, stream>>>(z, bnsc, bnsh, lin2_w, lin2_b, hout, i);
        float* t = hin; hin = hout; hout = t;
    }

    // --- output projection ---
    k_final<<<NN / 8, 256, 0, stream>>>(hin, w16, b16, out);
}

// Round 2
// 2053.264 us; speedup vs baseline: 1.7457x; 1.7457x over previous
//
#include <hip/hip_runtime.h>

#define NN 100000
#define IN_CH 128
#define HID 32
#define OUT_CH 64
#define N_LAYERS 16
#define NB1 2048            // grid-stride blocks for k_agg (8 blocks/CU)
#define EPS_MSG 1e-7f
#define EPS_SM 1e-16f
#define EPS_BN 1e-5f

// ---------------- CSR build ----------------

__global__ void k_hist(const int* __restrict__ dst, int* __restrict__ counts, int E) {
    int i = blockIdx.x * 256 + threadIdx.x;
    if (i < E) atomicAdd(&counts[dst[i]], 1);
}

__global__ void k_scan1(const int* __restrict__ counts, int* __restrict__ rowptr,
                        int* __restrict__ bsum, int n) {
    __shared__ int sh[1024];
    int t = threadIdx.x;
    int i = blockIdx.x * 1024 + t;
    int v = (i < n) ? counts[i] : 0;
    sh[t] = v;
    __syncthreads();
    for (int off = 1; off < 1024; off <<= 1) {
        int tmp = (t >= off) ? sh[t - off] : 0;
        __syncthreads();
        sh[t] += tmp;
        __syncthreads();
    }
    if (i < n) rowptr[i] = sh[t] - v;   // exclusive within chunk
    if (t == 1023) bsum[blockIdx.x] = sh[1023];
}

__global__ void k_scan2(int* __restrict__ bsum, int nb) {
    if (threadIdx.x == 0 && blockIdx.x == 0) {
        int acc = 0;
        for (int b = 0; b < nb; b++) { int v = bsum[b]; bsum[b] = acc; acc += v; }
    }
}

__global__ void k_scan3(int* __restrict__ rowptr, int* __restrict__ cursor,
                        const int* __restrict__ bsum, int n, int E) {
    int i = blockIdx.x * 256 + threadIdx.x;
    if (i < n) {
        int r = rowptr[i] + bsum[i >> 10];
        rowptr[i] = r;
        cursor[i] = r;
    }
    if (i == 0) rowptr[n] = E;
}

__global__ void k_scatter(const int* __restrict__ src, const int* __restrict__ dst,
                          int* __restrict__ cursor, int* __restrict__ col, int E) {
    int i = blockIdx.x * 256 + threadIdx.x;
    if (i < E) {
        int d = dst[i];
        int p = atomicAdd(&cursor[d], 1);
        col[p] = src[i];
    }
}

// ---------------- input projection: h0 = x @ w0 + b0 ----------------

__global__ __launch_bounds__(256) void k0(const float* __restrict__ x,
                                          const float* __restrict__ w0,
                                          const float* __restrict__ b0,
                                          float* __restrict__ h) {
    __shared__ float ws[IN_CH * HID];   // 16 KB
    __shared__ float xs[8][IN_CH];      // 4 KB
    int tid = threadIdx.x, c = tid & 31, g = tid >> 5;
    for (int k = tid; k < IN_CH * HID; k += 256) ws[k] = w0[k];
    int d = blockIdx.x * 8 + g;
    float4 xv = ((const float4*)(x + (size_t)d * IN_CH))[c];
    ((float4*)xs[g])[c] = xv;
    __syncthreads();
    float acc = b0[c];
#pragma unroll 16
    for (int k = 0; k < IN_CH; k++) acc += xs[g][k] * ws[k * HID + c];
    h[(size_t)d * HID + c] = acc;
}

// ---------------- per-layer: softmax-agg + residual + lin1 + BN partial sums ----------------

__global__ __launch_bounds__(256) void k_agg(const float* __restrict__ h,
                                             const int* __restrict__ rowptr,
                                             const int* __restrict__ col,
                                             const float* __restrict__ w1,
                                             const float* __restrict__ b1,
                                             float* __restrict__ z,
                                             float* __restrict__ zsum,
                                             int layer) {
    __shared__ float w1s[HID * 64];   // 8 KB
    __shared__ float b1s[64];
    __shared__ float outs[8][HID];
    __shared__ float red[256];
    int tid = threadIdx.x, c = tid & 31, g = tid >> 5;
    for (int k = tid; k < HID * 64; k += 256) w1s[k] = w1[layer * (HID * 64) + k];
    if (tid < 64) b1s[tid] = b1[layer * 64 + tid];
    float s0 = 0.f, s1 = 0.f, q0 = 0.f, q1 = 0.f;
    __syncthreads();

    for (int d0 = blockIdx.x * 8; d0 < NN; d0 += NB1 * 8) {
        int d = d0 + g;
        float out = 0.f;
        if (d < NN) {
            int r0 = rowptr[d], r1 = rowptr[d + 1];
            float den = 0.f, num = 0.f;
            // unroll-by-8 with batched loads: 8 col loads in flight, then 8
            // gathers in flight (MLP=8), predicated accumulate. col is padded
            // by 8 zero entries so OOB loads are safe.
            for (int e = r0; e < r1; e += 8) {
                int ss[8];
#pragma unroll
                for (int j = 0; j < 8; j++) ss[j] = col[e + j];
                float vv[8];
#pragma unroll
                for (int j = 0; j < 8; j++)
                    vv[j] = fmaxf(h[(size_t)ss[j] * HID + c], 0.f) + EPS_MSG;
#pragma unroll
                for (int j = 0; j < 8; j++) {
                    float ev = __expf(vv[j]);   // bounded: no max-subtraction needed
                    bool ok = (e + j) < r1;
                    den += ok ? ev : 0.f;
                    num += ok ? ev * vv[j] : 0.f;
                }
            }
            out = num / (den + EPS_SM) + h[(size_t)d * HID + c];
        }
        outs[g][c] = out;
        __syncthreads();
        if (d < NN) {
            float z0 = b1s[c], z1 = b1s[c + 32];
#pragma unroll
            for (int k = 0; k < HID; k++) {
                float o = outs[g][k];
                z0 += o * w1s[k * 64 + c];
                z1 += o * w1s[k * 64 + c + 32];
            }
            z[(size_t)d * 64 + c] = z0;
            z[(size_t)d * 64 + 32 + c] = z1;
            s0 += z0; s1 += z1; q0 += z0 * z0; q1 += z1 * z1;
        }
        __syncthreads();
    }

    // block-level reduce of BN partials, then one atomicAdd per channel
    float* acc = zsum + layer * 128;
    red[tid] = s0; __syncthreads();
    if (tid < 32) { float a = 0; for (int g2 = 0; g2 < 8; g2++) a += red[g2 * 32 + tid]; atomicAdd(&acc[tid], a); }
    __syncthreads();
    red[tid] = s1; __syncthreads();
    if (tid < 32) { float a = 0; for (int g2 = 0; g2 < 8; g2++) a += red[g2 * 32 + tid]; atomicAdd(&acc[32 + tid], a); }
    __syncthreads();
    red[tid] = q0; __syncthreads();
    if (tid < 32) { float a = 0; for (int g2 = 0; g2 < 8; g2++) a += red[g2 * 32 + tid]; atomicAdd(&acc[64 + tid], a); }
    __syncthreads();
    red[tid] = q1; __syncthreads();
    if (tid < 32) { float a = 0; for (int g2 = 0; g2 < 8; g2++) a += red[g2 * 32 + tid]; atomicAdd(&acc[96 + tid], a); }
}

// ---------------- BN apply + relu + lin2 + relu (BN stats finalized in-block) ----------------

__global__ __launch_bounds__(256) void k_bn2(const float* __restrict__ z,
                                             const float* __restrict__ zsum,
                                             const float* __restrict__ gamma,
                                             const float* __restrict__ beta,
                                             const float* __restrict__ w2,
                                             const float* __restrict__ b2,
                                             float* __restrict__ hout,
                                             int layer) {
    __shared__ float w2s[64 * HID];   // 8 KB
    __shared__ float zs[8][64];
    __shared__ float scs[64], shs[64];
    int tid = threadIdx.x, c = tid & 31, g = tid >> 5;
    for (int k = tid; k < 64 * HID; k += 256) w2s[k] = w2[layer * (64 * HID) + k];
    if (tid < 64) {
        float S = zsum[layer * 128 + tid];
        float Q = zsum[layer * 128 + 64 + tid];
        float mean = S * (1.0f / NN);
        float var = Q * (1.0f / NN) - mean * mean;
        float sc = gamma[layer * 64 + tid] * rsqrtf(var + EPS_BN);
        scs[tid] = sc;
        shs[tid] = beta[layer * 64 + tid] - mean * sc;
    }
    __syncthreads();
    int d = blockIdx.x * 8 + g;
    float z0 = z[(size_t)d * 64 + c] * scs[c] + shs[c];
    float z1 = z[(size_t)d * 64 + 32 + c] * scs[c + 32] + shs[c + 32];
    zs[g][c] = fmaxf(z0, 0.f);
    zs[g][c + 32] = fmaxf(z1, 0.f);
    __syncthreads();
    float acc = b2[layer * HID + c];
#pragma unroll
    for (int k = 0; k < 64; k++) acc += zs[g][k] * w2s[k * HID + c];
    hout[(size_t)d * HID + c] = fmaxf(acc, 0.f);
}

// ---------------- output projection: out = h @ w16 + b16 ----------------

__global__ __launch_bounds__(256) void k_final(const float* __restrict__ h,
                                               const float* __restrict__ w16,
                                               const float* __restrict__ b16,
                                               float* __restrict__ out) {
    __shared__ float ws[HID * OUT_CH];   // 8 KB
    __shared__ float hs[8][HID];
    int tid = threadIdx.x, c = tid & 31, g = tid >> 5;
    for (int k = tid; k < HID * OUT_CH; k += 256) ws[k] = w16[k];
    int d = blockIdx.x * 8 + g;
    hs[g][c] = h[(size_t)d * HID + c];
    __syncthreads();
    float o0 = b16[c], o1 = b16[c + 32];
#pragma unroll
    for (int k = 0; k < HID; k++) {
        float hv = hs[g][k];
        o0 += hv * ws[k * OUT_CH + c];
        o1 += hv * ws[k * OUT_CH + c + 32];
    }
    out[(size_t)d * OUT_CH + c] = o0;
    out[(size_t)d * OUT_CH + 32 + c] = o1;
}

// ---------------- host ----------------

extern "C" void kernel_launch(void* const* d_in, const int* in_sizes, int n_in,
                              void* d_out, int out_size, void* d_ws, size_t ws_size,
                              hipStream_t stream) {
    const float* x      = (const float*)d_in[0];
    const int*   ei     = (const int*)d_in[1];
    const float* w0     = (const float*)d_in[2];
    const float* b0     = (const float*)d_in[3];
    const float* lin1_w = (const float*)d_in[4];
    const float* lin1_b = (const float*)d_in[5];
    const float* gamma  = (const float*)d_in[6];
    const float* beta   = (const float*)d_in[7];
    const float* lin2_w = (const float*)d_in[8];
    const float* lin2_b = (const float*)d_in[9];
    const float* w16    = (const float*)d_in[10];
    const float* b16    = (const float*)d_in[11];
    float* out = (float*)d_out;

    const int E = in_sizes[1] / 2;
    const int* src = ei;
    const int* dst = ei + E;

    // workspace carve-up (all 256B-aligned)
    char* p = (char*)d_ws;
    auto alloc = [&](size_t bytes) {
        char* q = p;
        p += (bytes + 255) & ~(size_t)255;
        return q;
    };
    float* hA       = (float*)alloc((size_t)NN * HID * 4);
    float* hB       = (float*)alloc((size_t)NN * HID * 4);
    float* z        = (float*)alloc((size_t)NN * 64 * 4);
    int*   rowptr   = (int*)alloc((size_t)(NN + 1) * 4);
    int*   cursor   = (int*)alloc((size_t)NN * 4);
    int*   counts   = (int*)alloc((size_t)NN * 4);
    int*   col      = (int*)alloc((size_t)(E + 8) * 4);   // +8 pad for unroll OOB
    int*   bsum     = (int*)alloc(1024 * 4);
    float* zsum     = (float*)alloc((size_t)N_LAYERS * 128 * 4);
    (void)ws_size; (void)n_in; (void)out_size;

    // --- zero accumulators + CSR build (once per call; reused by all layers) ---
    hipMemsetAsync(counts, 0, (size_t)NN * 4, stream);
    hipMemsetAsync(zsum, 0, (size_t)N_LAYERS * 128 * 4, stream);
    hipMemsetAsync(col + E, 0, 8 * 4, stream);   // pad entries -> node 0 (safe loads)
    int egrid = (E + 255) / 256;
    k_hist<<<egrid, 256, 0, stream>>>(dst, counts, E);
    int b1g = (NN + 1023) / 1024;
    k_scan1<<<b1g, 1024, 0, stream>>>(counts, rowptr, bsum, NN);
    k_scan2<<<1, 1, 0, stream>>>(bsum, b1g);
    k_scan3<<<(NN + 255) / 256, 256, 0, stream>>>(rowptr, cursor, bsum, NN, E);
    k_scatter<<<egrid, 256, 0, stream>>>(src, dst, cursor, col, E);

    // --- input projection ---
    k0<<<NN / 8, 256, 0, stream>>>(x, w0, b0, hA);

    // --- 16 layers ---
    float* hin = hA;
    float* hout = hB;
    for (int i = 0; i < N_LAYERS; i++) {
        k_agg<<<NB1, 256, 0, stream>>>(hin, rowptr, col, lin1_w, lin1_b, z, zsum, i);
        k_bn2<<<NN / 8, 256, 0, stream>>>(z, zsum, gamma, beta, lin2_w, lin2_b, hout, i);
        float* t = hin; hin = hout; hout = t;
    }

    // --- output projection ---
    k_final<<<NN / 8, 256, 0, stream>>>(hin, w16, b16, out);
}

// Round 3
// 2051.718 us; speedup vs baseline: 1.7470x; 1.0008x over previous
//
#include <hip/hip_runtime.h>

#define NN 100000
#define IN_CH 128
#define HID 32
#define OUT_CH 64
#define N_LAYERS 16
#define NB1 2048            // k_agg blocks (4 waves each)
#define EPS_MSG 1e-7f
#define EPS_SM 1e-16f
#define EPS_BN 1e-5f

// ---------------- CSR build ----------------

__global__ void k_hist(const int* __restrict__ dst, int* __restrict__ counts, int E) {
    int i = blockIdx.x * 256 + threadIdx.x;
    if (i < E) atomicAdd(&counts[dst[i]], 1);
}

__global__ void k_scan1(const int* __restrict__ counts, int* __restrict__ rowptr,
                        int* __restrict__ bsum, int n) {
    __shared__ int sh[1024];
    int t = threadIdx.x;
    int i = blockIdx.x * 1024 + t;
    int v = (i < n) ? counts[i] : 0;
    sh[t] = v;
    __syncthreads();
    for (int off = 1; off < 1024; off <<= 1) {
        int tmp = (t >= off) ? sh[t - off] : 0;
        __syncthreads();
        sh[t] += tmp;
        __syncthreads();
    }
    if (i < n) rowptr[i] = sh[t] - v;   // exclusive within chunk
    if (t == 1023) bsum[blockIdx.x] = sh[1023];
}

__global__ void k_scan2(int* __restrict__ bsum, int nb) {
    if (threadIdx.x == 0 && blockIdx.x == 0) {
        int acc = 0;
        for (int b = 0; b < nb; b++) { int v = bsum[b]; bsum[b] = acc; acc += v; }
    }
}

__global__ void k_scan3(int* __restrict__ rowptr, int* __restrict__ cursor,
                        const int* __restrict__ bsum, int n, int E) {
    int i = blockIdx.x * 256 + threadIdx.x;
    if (i < n) {
        int r = rowptr[i] + bsum[i >> 10];
        rowptr[i] = r;
        cursor[i] = r;
    }
    if (i == 0) rowptr[n] = E;
}

__global__ void k_scatter(const int* __restrict__ src, const int* __restrict__ dst,
                          int* __restrict__ cursor, int* __restrict__ col, int E) {
    int i = blockIdx.x * 256 + threadIdx.x;
    if (i < E) {
        int d = dst[i];
        int p = atomicAdd(&cursor[d], 1);
        col[p] = src[i];
    }
}

// ---------------- input projection: h0 = x @ w0 + b0 ----------------

__global__ __launch_bounds__(256) void k0(const float* __restrict__ x,
                                          const float* __restrict__ w0,
                                          const float* __restrict__ b0,
                                          float* __restrict__ h) {
    __shared__ float ws[IN_CH * HID];   // 16 KB
    __shared__ float xs[8][IN_CH];      // 4 KB
    int tid = threadIdx.x, c = tid & 31, g = tid >> 5;
    for (int k = tid; k < IN_CH * HID; k += 256) ws[k] = w0[k];
    int d = blockIdx.x * 8 + g;
    float4 xv = ((const float4*)(x + (size_t)d * IN_CH))[c];
    ((float4*)xs[g])[c] = xv;
    __syncthreads();
    float acc = b0[c];
#pragma unroll 16
    for (int k = 0; k < IN_CH; k++) acc += xs[g][k] * ws[k * HID + c];
    h[(size_t)d * HID + c] = acc;
}

// ---------------- per-layer: softmax-agg + residual + lin1 + BN partials ----------------
// Wave-autonomous: each 32-lane half-wave owns one node (c = channel). No
// __syncthreads in the hot loop; lin1 done via __shfl within the half-wave.

__global__ __launch_bounds__(256) void k_agg(const float* __restrict__ h,
                                             const int* __restrict__ rowptr,
                                             const int* __restrict__ col,
                                             const float* __restrict__ w1,
                                             const float* __restrict__ b1,
                                             float* __restrict__ z,
                                             float* __restrict__ zsum,
                                             int layer) {
    __shared__ float w1s[HID * 64];   // 8 KB
    __shared__ float b1s[64];
    __shared__ float red[256];
    int tid = threadIdx.x, c = tid & 31;
    int half = (tid >> 5) & 1;                       // node slot within wave
    int wid = (blockIdx.x * 256 + tid) >> 6;         // global wave id
    for (int k = tid; k < HID * 64; k += 256) w1s[k] = w1[layer * (HID * 64) + k];
    if (tid < 64) b1s[tid] = b1[layer * 64 + tid];
    float s0 = 0.f, s1 = 0.f, q0 = 0.f, q1 = 0.f;
    __syncthreads();

    const int stride = NB1 * 4 * 2;                  // total waves * 2 nodes
    for (int d = wid * 2 + half; d < NN; d += stride) {
        int r0 = rowptr[d], r1 = rowptr[d + 1];
        float den = 0.f, num = 0.f;
        for (int e0 = r0; e0 < r1; e0 += 32) {
            int colv = col[e0 + c];                  // 32 edge srcs, one coalesced load
            int nb = r1 - e0; if (nb > 32) nb = 32;
            for (int j0 = 0; j0 < nb; j0 += 8) {
                float vv[8];
#pragma unroll
                for (int j = 0; j < 8; j++) {
                    int s = __shfl(colv, j0 + j, 32);
                    vv[j] = fmaxf(h[(size_t)s * HID + c], 0.f) + EPS_MSG;
                }
#pragma unroll
                for (int j = 0; j < 8; j++) {
                    float ev = __expf(vv[j]);        // bounded: no max-subtraction needed
                    bool ok = (j0 + j) < nb;
                    den += ok ? ev : 0.f;
                    num += ok ? ev * vv[j] : 0.f;
                }
            }
        }
        float out = num / (den + EPS_SM) + h[(size_t)d * HID + c];
        // lin1 via shuffle within the 32-lane half-wave
        float z0 = b1s[c], z1 = b1s[c + 32];
#pragma unroll
        for (int k = 0; k < HID; k++) {
            float o = __shfl(out, k, 32);
            z0 += o * w1s[k * 64 + c];
            z1 += o * w1s[k * 64 + c + 32];
        }
        z[(size_t)d * 64 + c] = z0;
        z[(size_t)d * 64 + 32 + c] = z1;
        s0 += z0; s1 += z1; q0 += z0 * z0; q1 += z1 * z1;
    }

    // block-level reduce of BN partials, then one atomicAdd per channel
    float* acc = zsum + layer * 128;
    red[tid] = s0; __syncthreads();
    if (tid < 32) { float a = 0; for (int g2 = 0; g2 < 8; g2++) a += red[g2 * 32 + tid]; atomicAdd(&acc[tid], a); }
    __syncthreads();
    red[tid] = s1; __syncthreads();
    if (tid < 32) { float a = 0; for (int g2 = 0; g2 < 8; g2++) a += red[g2 * 32 + tid]; atomicAdd(&acc[32 + tid], a); }
    __syncthreads();
    red[tid] = q0; __syncthreads();
    if (tid < 32) { float a = 0; for (int g2 = 0; g2 < 8; g2++) a += red[g2 * 32 + tid]; atomicAdd(&acc[64 + tid], a); }
    __syncthreads();
    red[tid] = q1; __syncthreads();
    if (tid < 32) { float a = 0; for (int g2 = 0; g2 < 8; g2++) a += red[g2 * 32 + tid]; atomicAdd(&acc[96 + tid], a); }
}

// ---------------- BN apply + relu + lin2 + relu (BN stats finalized in-block) ----------------

__global__ __launch_bounds__(256) void k_bn2(const float* __restrict__ z,
                                             const float* __restrict__ zsum,
                                             const float* __restrict__ gamma,
                                             const float* __restrict__ beta,
                                             const float* __restrict__ w2,
                                             const float* __restrict__ b2,
                                             float* __restrict__ hout,
                                             int layer) {
    __shared__ float w2s[64 * HID];   // 8 KB
    __shared__ float zs[8][64];
    __shared__ float scs[64], shs[64];
    int tid = threadIdx.x, c = tid & 31, g = tid >> 5;
    for (int k = tid; k < 64 * HID; k += 256) w2s[k] = w2[layer * (64 * HID) + k];
    if (tid < 64) {
        float S = zsum[layer * 128 + tid];
        float Q = zsum[layer * 128 + 64 + tid];
        float mean = S * (1.0f / NN);
        float var = Q * (1.0f / NN) - mean * mean;
        float sc = gamma[layer * 64 + tid] * rsqrtf(var + EPS_BN);
        scs[tid] = sc;
        shs[tid] = beta[layer * 64 + tid] - mean * sc;
    }
    __syncthreads();
    int d = blockIdx.x * 8 + g;
    float z0 = z[(size_t)d * 64 + c] * scs[c] + shs[c];
    float z1 = z[(size_t)d * 64 + 32 + c] * scs[c + 32] + shs[c + 32];
    zs[g][c] = fmaxf(z0, 0.f);
    zs[g][c + 32] = fmaxf(z1, 0.f);
    __syncthreads();
    float acc = b2[layer * HID + c];
#pragma unroll
    for (int k = 0; k < 64; k++) acc += zs[g][k] * w2s[k * HID + c];
    hout[(size_t)d * HID + c] = fmaxf(acc, 0.f);
}

// ---------------- output projection: out = h @ w16 + b16 ----------------

__global__ __launch_bounds__(256) void k_final(const float* __restrict__ h,
                                               const float* __restrict__ w16,
                                               const float* __restrict__ b16,
                                               float* __restrict__ out) {
    __shared__ float ws[HID * OUT_CH];   // 8 KB
    __shared__ float hs[8][HID];
    int tid = threadIdx.x, c = tid & 31, g = tid >> 5;
    for (int k = tid; k < HID * OUT_CH; k += 256) ws[k] = w16[k];
    int d = blockIdx.x * 8 + g;
    hs[g][c] = h[(size_t)d * HID + c];
    __syncthreads();
    float o0 = b16[c], o1 = b16[c + 32];
#pragma unroll
    for (int k = 0; k < HID; k++) {
        float hv = hs[g][k];
        o0 += hv * ws[k * OUT_CH + c];
        o1 += hv * ws[k * OUT_CH + c + 32];
    }
    out[(size_t)d * OUT_CH + c] = o0;
    out[(size_t)d * OUT_CH + 32 + c] = o1;
}

// ---------------- host ----------------

extern "C" void kernel_launch(void* const* d_in, const int* in_sizes, int n_in,
                              void* d_out, int out_size, void* d_ws, size_t ws_size,
                              hipStream_t stream) {
    const float* x      = (const float*)d_in[0];
    const int*   ei     = (const int*)d_in[1];
    const float* w0     = (const float*)d_in[2];
    const float* b0     = (const float*)d_in[3];
    const float* lin1_w = (const float*)d_in[4];
    const float* lin1_b = (const float*)d_in[5];
    const float* gamma  = (const float*)d_in[6];
    const float* beta   = (const float*)d_in[7];
    const float* lin2_w = (const float*)d_in[8];
    const float* lin2_b = (const float*)d_in[9];
    const float* w16    = (const float*)d_in[10];
    const float* b16    = (const float*)d_in[11];
    float* out = (float*)d_out;

    const int E = in_sizes[1] / 2;
    const int* src = ei;
    const int* dst = ei + E;

    // workspace carve-up (all 256B-aligned)
    char* p = (char*)d_ws;
    auto alloc = [&](size_t bytes) {
        char* q = p;
        p += (bytes + 255) & ~(size_t)255;
        return q;
    };
    float* hA       = (float*)alloc((size_t)NN * HID * 4);
    float* hB       = (float*)alloc((size_t)NN * HID * 4);
    float* z        = (float*)alloc((size_t)NN * 64 * 4);
    int*   rowptr   = (int*)alloc((size_t)(NN + 1) * 4);
    int*   cursor   = (int*)alloc((size_t)NN * 4);
    int*   counts   = (int*)alloc((size_t)NN * 4);
    int*   col      = (int*)alloc((size_t)(E + 32) * 4);   // +32 pad for chunked reads
    int*   bsum     = (int*)alloc(1024 * 4);
    float* zsum     = (float*)alloc((size_t)N_LAYERS * 128 * 4);
    (void)ws_size; (void)n_in; (void)out_size;

    // --- zero accumulators + CSR build (once per call; reused by all layers) ---
    hipMemsetAsync(counts, 0, (size_t)NN * 4, stream);
    hipMemsetAsync(zsum, 0, (size_t)N_LAYERS * 128 * 4, stream);
    hipMemsetAsync(col + E, 0, 32 * 4, stream);   // pad entries -> node 0 (safe loads)
    int egrid = (E + 255) / 256;
    k_hist<<<egrid, 256, 0, stream>>>(dst, counts, E);
    int b1g = (NN + 1023) / 1024;
    k_scan1<<<b1g, 1024, 0, stream>>>(counts, rowptr, bsum, NN);
    k_scan2<<<1, 1, 0, stream>>>(bsum, b1g);
    k_scan3<<<(NN + 255) / 256, 256, 0, stream>>>(rowptr, cursor, bsum, NN, E);
    k_scatter<<<egrid, 256, 0, stream>>>(src, dst, cursor, col, E);

    // --- input projection ---
    k0<<<NN / 8, 256, 0, stream>>>(x, w0, b0, hA);

    // --- 16 layers ---
    float* hin = hA;
    float* hout = hB;
    for (int i = 0; i < N_LAYERS; i++) {
        k_agg<<<NB1, 256, 0, stream>>>(hin, rowptr, col, lin1_w, lin1_b, z, zsum, i);
        k_bn2<<<NN / 8, 256, 0, stream>>>(z, zsum, gamma, beta, lin2_w, lin2_b, hout, i);
        float* t = hin; hin = hout; hout = t;
    }

    // --- output projection ---
    k_final<<<NN / 8, 256, 0, stream>>>(hin, w16, b16, out);
}